// Round 17
// baseline (72.573 us; speedup 1.0000x reference)
//
#include <hip/hip_runtime.h>
#include <hip/hip_bf16.h>

typedef __bf16 bf16_t;
typedef __bf16 bf16x4 __attribute__((ext_vector_type(4)));
typedef __bf16 bf16x8 __attribute__((ext_vector_type(8)));
typedef float f32x4 __attribute__((ext_vector_type(4)));
typedef float f32x16 __attribute__((ext_vector_type(16)));
typedef unsigned uint4v __attribute__((ext_vector_type(4)));

constexpr int B = 4, T = 4096, C = 1024, H = 64;

__device__ __forceinline__ void gll16(const void* g, void* l) {
  __builtin_amdgcn_global_load_lds(
      (const __attribute__((address_space(1))) void*)g,
      (__attribute__((address_space(3))) void*)l, 16, 0, 0);
}

__device__ __forceinline__ unsigned pk2(float x, float y) {
  union { bf16_t h[2]; unsigned u; } u_;
  u_.h[0] = (bf16_t)x; u_.h[1] = (bf16_t)y;
  return u_.u;
}

// ---------------------------------------------------------------------------
// Kernel 1: weights -> bf16, transposed WT[w][h][c]; Wq folded 0.125*log2e.
// ---------------------------------------------------------------------------
__global__ __launch_bounds__(256) void wconv_kernel(
    const float* __restrict__ Wk, const float* __restrict__ Wq,
    const float* __restrict__ Wv, bf16_t* __restrict__ WT) {
  int idx = blockIdx.x * 256 + threadIdx.x;
  if (idx >= 3 * H * C) return;
  int w = idx / (H * C);
  int rem = idx - w * H * C;
  int h = rem / C;
  int c = rem - h * C;
  const float* src = (w == 0) ? Wq : (w == 1) ? Wk : Wv;
  float f = src[c * H + h];
  if (w == 0) f *= 0.125f * 1.44269504088896f;
  WT[idx] = (bf16_t)f;
}

// ---------------------------------------------------------------------------
// Kernel 2: fused QKV projection (R15-verified; kappa reverted).
// 512-thread blocks: 8 waves = 2 row-halves x 4 col-quarters (3 nt each).
// ---------------------------------------------------------------------------
__global__ __launch_bounds__(512, 2) void proj_kernel(
    const float* __restrict__ x, const bf16_t* __restrict__ WT,
    bf16_t* __restrict__ qb, bf16_t* __restrict__ kb, bf16_t* __restrict__ vT) {
  __shared__ __align__(16) char xsm[2][8192];   // 32 rows x 256B, swizzled
  __shared__ __align__(16) char wsm[2][24576];  // 192 rows x 128B, swizzled
  const int tid = threadIdx.x;
  const int lane = tid & 63;
  const int wave = tid >> 6;          // 0..7
  const int lr = lane & 15, lg = lane >> 4;
  const int rw = wave & 1;            // row-half 0..1
  const int cw = wave >> 1;           // col-quarter 0..3
  const int m0 = blockIdx.x * 32;

  f32x4 acc[3];
#pragma unroll
  for (int i = 0; i < 3; ++i) acc[i] = f32x4{0.f, 0.f, 0.f, 0.f};

  auto stage = [&](int buf, int ks) {
    {  // x tile: 32 rows x 256B = 512 segs, 1/thread
      const int row = tid >> 4;
      const int scb = ((tid & 15) * 16) ^ ((row & 7) << 4);
      gll16(x + (size_t)(m0 + row) * C + ks + (scb >> 2),
            &xsm[buf][tid * 16]);
    }
#pragma unroll
    for (int c = 0; c < 3; ++c) {  // W tile: 192 rows x 128B = 1536 segs
      const int row = c * 64 + (tid >> 3);
      const int scb = ((tid & 7) * 16) ^ ((row & 7) << 4);
      gll16(WT + (size_t)row * C + ks + (scb >> 1),
            &wsm[buf][c * 8192 + tid * 16]);
    }
  };

  stage(0, 0);
  __syncthreads();
  for (int t = 0; t < 16; ++t) {
    const int cur = t & 1;
    if (t < 15) stage(cur ^ 1, (t + 1) * 64);
    const char* xb_ = xsm[cur];
    const char* wb_ = wsm[cur];
#pragma unroll
    for (int ksub = 0; ksub < 2; ++ksub) {
      const int xrow = rw * 16 + lr;
      const int xsw = (xrow & 7) << 4;
      const int cb = ksub * 128 + lg * 32;
      const f32x4 xa = *(const f32x4*)(xb_ + xrow * 256 + (cb ^ xsw));
      const f32x4 xv = *(const f32x4*)(xb_ + xrow * 256 + ((cb + 16) ^ xsw));
      bf16x8 af;
      af[0] = (bf16_t)xa[0]; af[1] = (bf16_t)xa[1];
      af[2] = (bf16_t)xa[2]; af[3] = (bf16_t)xa[3];
      af[4] = (bf16_t)xv[0]; af[5] = (bf16_t)xv[1];
      af[6] = (bf16_t)xv[2]; af[7] = (bf16_t)xv[3];
#pragma unroll
      for (int t2 = 0; t2 < 3; ++t2) {
        const int nt = cw * 3 + t2;
        const int wrow = nt * 16 + lr;
        const bf16x8 wf = *(const bf16x8*)(
            wb_ + wrow * 128 + ((ksub * 64 + lg * 16) ^ ((wrow & 7) << 4)));
        acc[t2] = __builtin_amdgcn_mfma_f32_16x16x32_bf16(af, wf, acc[t2], 0, 0, 0);
      }
    }
    __syncthreads();
  }

#pragma unroll
  for (int t2 = 0; t2 < 3; ++t2) {
    const int nt = cw * 3 + t2;
    const int wsel = nt >> 2;
    const int h = (nt & 3) * 16 + lr;
#pragma unroll
    for (int r = 0; r < 4; ++r) {
      const int row = m0 + rw * 16 + lg * 4 + r;
      bf16_t val = (bf16_t)acc[t2][r];
      if (wsel == 0)
        qb[(size_t)row * H + h] = val;
      else if (wsel == 1)
        kb[(size_t)row * H + h] = val;
      else
        vT[((size_t)(row >> 12) * H + h) * T + (row & (T - 1))] = val;
    }
  }
}

// ---------------------------------------------------------------------------
// Kernel 3: causal flash attention, 2-way KV-split (R12/R15-verified chunk
// body with shfl exchange). LDS shrunk for occupancy: SINGLE-buffer staging
// (32 KB; compute -> barrier -> stage -> barrier, R14-verified ordering) +
// 2-phase epilogue (red [4][64][36] padded, R14-verified indexing).
// Union ~38 KB; natural VGPR (~68, no pin!) -> 3 blocks/CU = 24 waves/CU.
// ---------------------------------------------------------------------------
__global__ __launch_bounds__(512) void flash_kernel(
    const bf16_t* __restrict__ qb, const bf16_t* __restrict__ kb,
    const bf16_t* __restrict__ vT, float* __restrict__ pacc,
    float* __restrict__ pml) {
  __shared__ union {
    struct {
      __align__(16) char k[16384];  // [128 keys][128B], swizzled
      __align__(16) char v[16384];  // [64 h][256B], swizzled
    } st;
    struct {
      __align__(16) float acc[4][64][36];  // padded: 144B row stride
      float ml[4][32][2];
    } red;
  } sm;

  const int tid = threadIdx.x;
  const int lane = tid & 63;
  const int wave = tid >> 6;
  const int ql = lane & 31;
  const int hi = lane >> 5;
  const int hi8 = hi * 8, hi16 = hi * 16, hi4 = hi * 4;
  const int p = wave >> 2;  // q-tile 0..1
  const int s = wave & 3;   // 32-key window within chunk

  const int bid = blockIdx.x;
  const int half = bid >> 8;            // 0 | 1
  const int r_ = bid & 255;
  const int qj = 63 - (r_ >> 2);        // LPT order
  const int b = r_ & 3;
  const int widx = (b * 64 + qj) * 2 + half;
  const int q0base = qj * 64;
  const int qt0 = q0base + p * 32;
  const bf16_t* Kb = kb + (size_t)b * T * H;
  const bf16_t* Vb = vT + (size_t)b * H * T;

  const bf16_t* qp = qb + (size_t)(b * T + qt0 + ql) * H;
  const bf16x8 qf0 = *(const bf16x8*)(qp + hi8);
  const bf16x8 qf1 = *(const bf16x8*)(qp + 16 + hi8);
  const bf16x8 qf2 = *(const bf16x8*)(qp + 32 + hi8);
  const bf16x8 qf3 = *(const bf16x8*)(qp + 48 + hi8);

  f32x16 acc0, acc1;
#pragma unroll
  for (int i = 0; i < 16; ++i) { acc0[i] = 0.f; acc1[i] = 0.f; }
  float m = -1e30f, lsum = 0.f;

  auto stage = [&](int k0) {
#pragma unroll
    for (int i = 0; i < 2; ++i) {  // K: 128 rows x 128B
      const int seg = tid + i * 512;
      const int row = seg >> 3, sl = seg & 7;
      const int byt = (sl * 16) ^ ((row & 7) << 4);
      gll16(Kb + (size_t)(k0 + row) * H + (byt >> 1), &sm.st.k[seg * 16]);
    }
#pragma unroll
    for (int i = 0; i < 2; ++i) {  // V: 64 rows x 256B
      const int seg = tid + i * 512;
      const int row = seg >> 4, sl = seg & 15;
      const int byt = (sl * 16) ^ ((row & 7) << 4);
      gll16(Vb + (size_t)row * T + k0 + (byt >> 1), &sm.st.v[seg * 16]);
    }
  };

  const int nc = (q0base + 64 + 127) >> 7;            // total 128-key chunks
  const int nh = half ? (nc >> 1) : ((nc + 1) >> 1);  // this half's chunks
  if (nh > 0) stage(half * 128);
  __syncthreads();

  for (int t = 0; t < nh; ++t) {
    const int ci = 2 * t + half;
    const int kk = ci * 128 + s * 32;
    if (kk <= qt0) {  // wave-uniform causal skip
      const int kr = s * 32 + ql;
      const int ksw = (kr & 7) << 4;
      const char* kbase = &sm.st.k[kr * 128];
      const bf16x8 kf0 = *(const bf16x8*)(kbase + ((0 + hi16) ^ ksw));
      const bf16x8 kf1 = *(const bf16x8*)(kbase + ((32 + hi16) ^ ksw));
      const bf16x8 kf2 = *(const bf16x8*)(kbase + ((64 + hi16) ^ ksw));
      const bf16x8 kf3 = *(const bf16x8*)(kbase + ((96 + hi16) ^ ksw));
      f32x16 S;
#pragma unroll
      for (int i = 0; i < 16; ++i) S[i] = 0.f;
      S = __builtin_amdgcn_mfma_f32_32x32x16_bf16(kf0, qf0, S, 0, 0, 0);
      S = __builtin_amdgcn_mfma_f32_32x32x16_bf16(kf1, qf1, S, 0, 0, 0);
      S = __builtin_amdgcn_mfma_f32_32x32x16_bf16(kf2, qf2, S, 0, 0, 0);
      S = __builtin_amdgcn_mfma_f32_32x32x16_bf16(kf3, qf3, S, 0, 0, 0);
      const int vsw = (ql & 7) << 4;
      const char* vb0 = &sm.st.v[ql * 256];
      const char* vb1 = &sm.st.v[(32 + ql) * 256];
      const bf16x8 vf00 = *(const bf16x8*)(vb0 + ((s * 64 + hi16) ^ vsw));
      const bf16x8 vf01 = *(const bf16x8*)(vb0 + ((s * 64 + 32 + hi16) ^ vsw));
      const bf16x8 vf10 = *(const bf16x8*)(vb1 + ((s * 64 + hi16) ^ vsw));
      const bf16x8 vf11 = *(const bf16x8*)(vb1 + ((s * 64 + 32 + hi16) ^ vsw));
      if (kk + 31 > qt0) {  // diagonal-crossing window only
        const int qg = qt0 + ql;
#pragma unroll
        for (int reg = 0; reg < 16; ++reg) {
          const int keyg = kk + (reg & 3) + 8 * (reg >> 2) + hi4;
          S[reg] = (keyg > qg) ? -1e30f : S[reg];
        }
      }
      // online softmax (exp2 domain), defer-max; verified shfl reduces
      float t0 = fmaxf(fmaxf(fmaxf(S[0], S[1]), fmaxf(S[2], S[3])),
                       fmaxf(fmaxf(S[4], S[5]), fmaxf(S[6], S[7])));
      float t1 = fmaxf(fmaxf(fmaxf(S[8], S[9]), fmaxf(S[10], S[11])),
                       fmaxf(fmaxf(S[12], S[13]), fmaxf(S[14], S[15])));
      float tmax = fmaxf(t0, t1);
      tmax = fmaxf(tmax, __shfl_xor(tmax, 32));
      if (!__all(tmax <= m + 11.5f)) {
        const float mn = fmaxf(m, tmax);
        const float alpha = __builtin_amdgcn_exp2f(m - mn);
        m = mn;
        lsum *= alpha;
#pragma unroll
        for (int i = 0; i < 16; ++i) { acc0[i] *= alpha; acc1[i] *= alpha; }
      }
#pragma unroll
      for (int reg = 0; reg < 16; ++reg)
        S[reg] = __builtin_amdgcn_exp2f(S[reg] - m);
      float rs = ((S[0] + S[1]) + (S[2] + S[3])) + ((S[4] + S[5]) + (S[6] + S[7])) +
                 ((S[8] + S[9]) + (S[10] + S[11])) + ((S[12] + S[13]) + (S[14] + S[15]));
      rs += __shfl_xor(rs, 32);
      lsum += rs;
      // P -> bf16 B-fragments: verified pack + shfl_xor(32) + select
      const unsigned a0 = pk2(S[0], S[1]), a1 = pk2(S[2], S[3]);
      const unsigned b0 = pk2(S[4], S[5]), b1 = pk2(S[6], S[7]);
      const unsigned c0 = pk2(S[8], S[9]), c1 = pk2(S[10], S[11]);
      const unsigned d0 = pk2(S[12], S[13]), d1 = pk2(S[14], S[15]);
      const unsigned pa0 = (unsigned)__shfl_xor((int)a0, 32);
      const unsigned pa1 = (unsigned)__shfl_xor((int)a1, 32);
      const unsigned pb0 = (unsigned)__shfl_xor((int)b0, 32);
      const unsigned pb1 = (unsigned)__shfl_xor((int)b1, 32);
      const unsigned pc0 = (unsigned)__shfl_xor((int)c0, 32);
      const unsigned pc1 = (unsigned)__shfl_xor((int)c1, 32);
      const unsigned pd0 = (unsigned)__shfl_xor((int)d0, 32);
      const unsigned pd1 = (unsigned)__shfl_xor((int)d1, 32);
      const bool hb_ = (hi != 0);
      uint4v wk0, wk1;
      wk0[0] = hb_ ? pb0 : a0;  wk0[1] = hb_ ? pb1 : a1;
      wk0[2] = hb_ ? b0 : pa0;  wk0[3] = hb_ ? b1 : pa1;
      wk1[0] = hb_ ? pd0 : c0;  wk1[1] = hb_ ? pd1 : c1;
      wk1[2] = hb_ ? d0 : pc0;  wk1[3] = hb_ ? d1 : pc1;
      const bf16x8 pf0 = __builtin_bit_cast(bf16x8, wk0);
      const bf16x8 pf1 = __builtin_bit_cast(bf16x8, wk1);
      acc0 = __builtin_amdgcn_mfma_f32_32x32x16_bf16(vf00, pf0, acc0, 0, 0, 0);
      acc0 = __builtin_amdgcn_mfma_f32_32x32x16_bf16(vf01, pf1, acc0, 0, 0, 0);
      acc1 = __builtin_amdgcn_mfma_f32_32x32x16_bf16(vf10, pf0, acc1, 0, 0, 0);
      acc1 = __builtin_amdgcn_mfma_f32_32x32x16_bf16(vf11, pf1, acc1, 0, 0, 0);
    }
    __syncthreads();  // A: all waves done reading st
    if (t + 1 < nh) stage((2 * (t + 1) + half) * 128);
    __syncthreads();  // B: stage drained (syncthreads waits vmcnt) + visible
  }

  // ---- epilogue: 2 phases over q-tile p (R14-verified, padded stride 36)
#pragma unroll
  for (int ph = 0; ph < 2; ++ph) {
    __syncthreads();  // st quiet (ph0) / prior phase reads done (ph1)
    if (p == ph) {
      const int w4 = wave & 3;
#pragma unroll
      for (int g = 0; g < 4; ++g) {
        f32x4 t0, t1;
#pragma unroll
        for (int i = 0; i < 4; ++i) { t0[i] = acc0[g * 4 + i]; t1[i] = acc1[g * 4 + i]; }
        *(f32x4*)&sm.red.acc[w4][lane][g * 4] = t0;
        *(f32x4*)&sm.red.acc[w4][lane][16 + g * 4] = t1;
      }
      if (lane < 32) {
        sm.red.ml[w4][lane][0] = m;
        sm.red.ml[w4][lane][1] = lsum;
      }
    }
    __syncthreads();
    if (wave < 4) {  // reader: tile ph, h-block = wave
      const int s4 = wave;
      const int hrow0 = (s4 & 1) * 16 + hi8;
      const int nt = s4 >> 1;
      const int rb = nt * 16 + ((hrow0 >> 3) << 2);
      float mw[4], lw[4];
#pragma unroll
      for (int w2 = 0; w2 < 4; ++w2) {
        mw[w2] = sm.red.ml[w2][ql][0];
        lw[w2] = sm.red.ml[w2][ql][1];
      }
      const float M = fmaxf(fmaxf(mw[0], mw[1]), fmaxf(mw[2], mw[3]));
      float L = 0.f;
      f32x4 o0 = f32x4{0.f, 0.f, 0.f, 0.f}, o1 = f32x4{0.f, 0.f, 0.f, 0.f};
#pragma unroll
      for (int w2 = 0; w2 < 4; ++w2) {
        const float e = __builtin_amdgcn_exp2f(mw[w2] - M);
        L += e * lw[w2];
        const f32x4 A0 = *(const f32x4*)&sm.red.acc[w2][ql][rb];
        const f32x4 A1 = *(const f32x4*)&sm.red.acc[w2][ql + 32][rb];
        o0[0] += e * A0[0]; o0[1] += e * A0[1]; o0[2] += e * A0[2]; o0[3] += e * A0[3];
        o1[0] += e * A1[0]; o1[1] += e * A1[1]; o1[2] += e * A1[2]; o1[3] += e * A1[3];
      }
      float* pa = pacc + (((size_t)widx * 64) + ph * 32 + ql) * 64 + s4 * 16 + hi8;
      *(f32x4*)(pa) = o0;
      *(f32x4*)(pa + 4) = o1;
      if (s4 == 0 && hi == 0) {
        float* pm = pml + (((size_t)widx * 64) + ph * 32 + ql) * 2;
        pm[0] = M;
        pm[1] = L;
      }
    }
  }
}

// ---------------------------------------------------------------------------
// Kernel 4: merge the two KV-halves -> final output (R12-verified).
// ---------------------------------------------------------------------------
__global__ __launch_bounds__(256) void comb_kernel(
    const float* __restrict__ pacc, const float* __restrict__ pml,
    float* __restrict__ out) {
  const int g = blockIdx.x;  // b*64 + qj
  const int qj = g & 63, b = g >> 6;
  const int t = threadIdx.x;
  const int q = t & 63, hq = t >> 6;
  const size_t i0 = (size_t)(2 * g) * 64 + q;
  const size_t i1 = (size_t)(2 * g + 1) * 64 + q;
  const float m0 = pml[i0 * 2], l0 = pml[i0 * 2 + 1];
  const float m1 = pml[i1 * 2], l1 = pml[i1 * 2 + 1];
  const float M = fmaxf(m0, m1);
  const float e0 = __builtin_amdgcn_exp2f(m0 - M);
  const float e1 = __builtin_amdgcn_exp2f(m1 - M);
  const float invL = 1.0f / (e0 * l0 + e1 * l1);
  const float* A0 = pacc + i0 * 64 + hq * 16;
  const float* A1 = pacc + i1 * 64 + hq * 16;
  float* op = out + ((size_t)b * T + qj * 64 + q) * H + hq * 16;
#pragma unroll
  for (int j = 0; j < 4; ++j) {
    const f32x4 x0 = *(const f32x4*)(A0 + j * 4);
    const f32x4 x1 = *(const f32x4*)(A1 + j * 4);
    f32x4 r;
#pragma unroll
    for (int i2 = 0; i2 < 4; ++i2) r[i2] = (e0 * x0[i2] + e1 * x1[i2]) * invL;
    *(f32x4*)(op + j * 4) = r;
  }
}

// ---------------------------------------------------------------------------
extern "C" void kernel_launch(void* const* d_in, const int* in_sizes, int n_in,
                              void* d_out, int out_size, void* d_ws,
                              size_t ws_size, hipStream_t stream) {
  const float* x = (const float*)d_in[0];
  const float* Wk = (const float*)d_in[1];
  const float* Wq = (const float*)d_in[2];
  const float* Wv = (const float*)d_in[3];
  float* out = (float*)d_out;
  char* ws = (char*)d_ws;
  const size_t SZ = (size_t)B * T * H * sizeof(bf16_t);  // 2 MB each
  bf16_t* qb = (bf16_t*)ws;
  bf16_t* kb = (bf16_t*)(ws + SZ);
  bf16_t* vT = (bf16_t*)(ws + 2 * SZ);
  bf16_t* WT = (bf16_t*)(ws + 3 * SZ);          // 384 KB
  float* pml = (float*)(ws + 7 * 1024 * 1024);  // 512*64*2 f32 = 256 KB
  float* pacc = (float*)(ws + 8 * 1024 * 1024); // 512*64*64 f32 = 8 MB

  wconv_kernel<<<(3 * H * C + 255) / 256, 256, 0, stream>>>(Wk, Wq, Wv, WT);
  proj_kernel<<<(B * T) / 32, 512, 0, stream>>>(x, WT, qb, kb, vT);
  flash_kernel<<<dim3(512), 512, 0, stream>>>(qb, kb, vT, pacc, pml);
  comb_kernel<<<dim3(256), 256, 0, stream>>>(pacc, pml, out);
}

// Round 18
// 64.108 us; speedup vs baseline: 1.1320x; 1.1320x over previous
//
#include <hip/hip_runtime.h>
#include <hip/hip_bf16.h>

typedef __bf16 bf16_t;
typedef __bf16 bf16x4 __attribute__((ext_vector_type(4)));
typedef __bf16 bf16x8 __attribute__((ext_vector_type(8)));
typedef float f32x4 __attribute__((ext_vector_type(4)));
typedef float f32x16 __attribute__((ext_vector_type(16)));
typedef unsigned uint4v __attribute__((ext_vector_type(4)));

constexpr int B = 4, T = 4096, C = 1024, H = 64;

__device__ __forceinline__ void gll16(const void* g, void* l) {
  __builtin_amdgcn_global_load_lds(
      (const __attribute__((address_space(1))) void*)g,
      (__attribute__((address_space(3))) void*)l, 16, 0, 0);
}

__device__ __forceinline__ unsigned pk2(float x, float y) {
  union { bf16_t h[2]; unsigned u; } u_;
  u_.h[0] = (bf16_t)x; u_.h[1] = (bf16_t)y;
  return u_.u;
}

// ---------------------------------------------------------------------------
// Kernel 1: weights -> bf16, transposed WT[w][h][c]; Wq folded 0.125*log2e.
// ---------------------------------------------------------------------------
__global__ __launch_bounds__(256) void wconv_kernel(
    const float* __restrict__ Wk, const float* __restrict__ Wq,
    const float* __restrict__ Wv, bf16_t* __restrict__ WT) {
  int idx = blockIdx.x * 256 + threadIdx.x;
  if (idx >= 3 * H * C) return;
  int w = idx / (H * C);
  int rem = idx - w * H * C;
  int h = rem / C;
  int c = rem - h * C;
  const float* src = (w == 0) ? Wq : (w == 1) ? Wk : Wv;
  float f = src[c * H + h];
  if (w == 0) f *= 0.125f * 1.44269504088896f;
  WT[idx] = (bf16_t)f;
}

// ---------------------------------------------------------------------------
// Kernel 2: fused QKV projection (R15-verified).
// 512-thread blocks: 8 waves = 2 row-halves x 4 col-quarters (3 nt each).
// Grid 512 -> 16 resident waves/CU (2 blocks x 8 waves).
// ---------------------------------------------------------------------------
__global__ __launch_bounds__(512, 2) void proj_kernel(
    const float* __restrict__ x, const bf16_t* __restrict__ WT,
    bf16_t* __restrict__ qb, bf16_t* __restrict__ kb, bf16_t* __restrict__ vT) {
  __shared__ __align__(16) char xsm[2][8192];   // 32 rows x 256B, swizzled
  __shared__ __align__(16) char wsm[2][24576];  // 192 rows x 128B, swizzled
  const int tid = threadIdx.x;
  const int lane = tid & 63;
  const int wave = tid >> 6;          // 0..7
  const int lr = lane & 15, lg = lane >> 4;
  const int rw = wave & 1;            // row-half 0..1
  const int cw = wave >> 1;           // col-quarter 0..3
  const int m0 = blockIdx.x * 32;

  f32x4 acc[3];
#pragma unroll
  for (int i = 0; i < 3; ++i) acc[i] = f32x4{0.f, 0.f, 0.f, 0.f};

  auto stage = [&](int buf, int ks) {
    {  // x tile: 32 rows x 256B = 512 segs, 1/thread
      const int row = tid >> 4;
      const int scb = ((tid & 15) * 16) ^ ((row & 7) << 4);
      gll16(x + (size_t)(m0 + row) * C + ks + (scb >> 2),
            &xsm[buf][tid * 16]);
    }
#pragma unroll
    for (int c = 0; c < 3; ++c) {  // W tile: 192 rows x 128B = 1536 segs
      const int row = c * 64 + (tid >> 3);
      const int scb = ((tid & 7) * 16) ^ ((row & 7) << 4);
      gll16(WT + (size_t)row * C + ks + (scb >> 1),
            &wsm[buf][c * 8192 + tid * 16]);
    }
  };

  stage(0, 0);
  __syncthreads();
  for (int t = 0; t < 16; ++t) {
    const int cur = t & 1;
    if (t < 15) stage(cur ^ 1, (t + 1) * 64);
    const char* xb_ = xsm[cur];
    const char* wb_ = wsm[cur];
#pragma unroll
    for (int ksub = 0; ksub < 2; ++ksub) {
      const int xrow = rw * 16 + lr;
      const int xsw = (xrow & 7) << 4;
      const int cb = ksub * 128 + lg * 32;
      const f32x4 xa = *(const f32x4*)(xb_ + xrow * 256 + (cb ^ xsw));
      const f32x4 xv = *(const f32x4*)(xb_ + xrow * 256 + ((cb + 16) ^ xsw));
      bf16x8 af;
      af[0] = (bf16_t)xa[0]; af[1] = (bf16_t)xa[1];
      af[2] = (bf16_t)xa[2]; af[3] = (bf16_t)xa[3];
      af[4] = (bf16_t)xv[0]; af[5] = (bf16_t)xv[1];
      af[6] = (bf16_t)xv[2]; af[7] = (bf16_t)xv[3];
#pragma unroll
      for (int t2 = 0; t2 < 3; ++t2) {
        const int nt = cw * 3 + t2;
        const int wrow = nt * 16 + lr;
        const bf16x8 wf = *(const bf16x8*)(
            wb_ + wrow * 128 + ((ksub * 64 + lg * 16) ^ ((wrow & 7) << 4)));
        acc[t2] = __builtin_amdgcn_mfma_f32_16x16x32_bf16(af, wf, acc[t2], 0, 0, 0);
      }
    }
    __syncthreads();
  }

#pragma unroll
  for (int t2 = 0; t2 < 3; ++t2) {
    const int nt = cw * 3 + t2;
    const int wsel = nt >> 2;
    const int h = (nt & 3) * 16 + lr;
#pragma unroll
    for (int r = 0; r < 4; ++r) {
      const int row = m0 + rw * 16 + lg * 4 + r;
      bf16_t val = (bf16_t)acc[t2][r];
      if (wsel == 0)
        qb[(size_t)row * H + h] = val;
      else if (wsel == 1)
        kb[(size_t)row * H + h] = val;
      else
        vT[((size_t)(row >> 12) * H + h) * T + (row & (T - 1))] = val;
    }
  }
}

// ---------------------------------------------------------------------------
// Kernel 3: causal flash attention, 2-way KV-split (R12-verified), with
// epilogue LDS pad 32->36 f32 (R15-verified). Double-buffered staging.
// ---------------------------------------------------------------------------
__global__ __launch_bounds__(512) void flash_kernel(
    const bf16_t* __restrict__ qb, const bf16_t* __restrict__ kb,
    const bf16_t* __restrict__ vT, float* __restrict__ pacc,
    float* __restrict__ pml) {
  __shared__ union {
    struct {
      __align__(16) char k[2][16384];  // [buf][128 keys][128B], swizzled
      __align__(16) char v[2][16384];  // [buf][64 h][256B], swizzled
    } st;
    struct {
      __align__(16) float acc[8][64][36];  // padded: 144B row stride
      float ml[8][32][2];
    } red;
  } sm;

  const int tid = threadIdx.x;
  const int lane = tid & 63;
  const int wave = tid >> 6;
  const int ql = lane & 31;
  const int hi = lane >> 5;
  const int hi8 = hi * 8, hi16 = hi * 16, hi4 = hi * 4;
  const int p = wave >> 2;  // q-tile 0..1
  const int s = wave & 3;   // 32-key window within chunk

  const int bid = blockIdx.x;
  const int half = bid >> 8;            // 0 | 1
  const int r_ = bid & 255;
  const int qj = 63 - (r_ >> 2);        // LPT order
  const int b = r_ & 3;
  const int widx = (b * 64 + qj) * 2 + half;
  const int q0base = qj * 64;
  const int qt0 = q0base + p * 32;
  const bf16_t* Kb = kb + (size_t)b * T * H;
  const bf16_t* Vb = vT + (size_t)b * H * T;

  const bf16_t* qp = qb + (size_t)(b * T + qt0 + ql) * H;
  const bf16x8 qf0 = *(const bf16x8*)(qp + hi8);
  const bf16x8 qf1 = *(const bf16x8*)(qp + 16 + hi8);
  const bf16x8 qf2 = *(const bf16x8*)(qp + 32 + hi8);
  const bf16x8 qf3 = *(const bf16x8*)(qp + 48 + hi8);

  f32x16 acc0, acc1;
#pragma unroll
  for (int i = 0; i < 16; ++i) { acc0[i] = 0.f; acc1[i] = 0.f; }
  float m = -1e30f, lsum = 0.f;

  auto stage = [&](int buf, int k0) {
#pragma unroll
    for (int i = 0; i < 2; ++i) {  // K: 128 rows x 128B
      const int seg = tid + i * 512;
      const int row = seg >> 3, sl = seg & 7;
      const int byt = (sl * 16) ^ ((row & 7) << 4);
      gll16(Kb + (size_t)(k0 + row) * H + (byt >> 1), &sm.st.k[buf][seg * 16]);
    }
#pragma unroll
    for (int i = 0; i < 2; ++i) {  // V: 64 rows x 256B
      const int seg = tid + i * 512;
      const int row = seg >> 4, sl = seg & 15;
      const int byt = (sl * 16) ^ ((row & 7) << 4);
      gll16(Vb + (size_t)row * T + k0 + (byt >> 1), &sm.st.v[buf][seg * 16]);
    }
  };

  const int nc = (q0base + 64 + 127) >> 7;            // total 128-key chunks
  const int nh = half ? (nc >> 1) : ((nc + 1) >> 1);  // this half's chunks
  if (nh > 0) stage(0, half * 128);
  __syncthreads();

  for (int t = 0; t < nh; ++t) {
    const int cur = t & 1;
    const int ci = 2 * t + half;
    if (t + 1 < nh) stage(cur ^ 1, (2 * (t + 1) + half) * 128);
    const int kk = ci * 128 + s * 32;
    if (kk <= qt0) {  // wave-uniform causal skip
      const int kr = s * 32 + ql;
      const int ksw = (kr & 7) << 4;
      const char* kbase = &sm.st.k[cur][kr * 128];
      const bf16x8 kf0 = *(const bf16x8*)(kbase + ((0 + hi16) ^ ksw));
      const bf16x8 kf1 = *(const bf16x8*)(kbase + ((32 + hi16) ^ ksw));
      const bf16x8 kf2 = *(const bf16x8*)(kbase + ((64 + hi16) ^ ksw));
      const bf16x8 kf3 = *(const bf16x8*)(kbase + ((96 + hi16) ^ ksw));
      f32x16 S;
#pragma unroll
      for (int i = 0; i < 16; ++i) S[i] = 0.f;
      S = __builtin_amdgcn_mfma_f32_32x32x16_bf16(kf0, qf0, S, 0, 0, 0);
      S = __builtin_amdgcn_mfma_f32_32x32x16_bf16(kf1, qf1, S, 0, 0, 0);
      S = __builtin_amdgcn_mfma_f32_32x32x16_bf16(kf2, qf2, S, 0, 0, 0);
      S = __builtin_amdgcn_mfma_f32_32x32x16_bf16(kf3, qf3, S, 0, 0, 0);
      const int vsw = (ql & 7) << 4;
      const char* vb0 = &sm.st.v[cur][ql * 256];
      const char* vb1 = &sm.st.v[cur][(32 + ql) * 256];
      const bf16x8 vf00 = *(const bf16x8*)(vb0 + ((s * 64 + hi16) ^ vsw));
      const bf16x8 vf01 = *(const bf16x8*)(vb0 + ((s * 64 + 32 + hi16) ^ vsw));
      const bf16x8 vf10 = *(const bf16x8*)(vb1 + ((s * 64 + hi16) ^ vsw));
      const bf16x8 vf11 = *(const bf16x8*)(vb1 + ((s * 64 + 32 + hi16) ^ vsw));
      if (kk + 31 > qt0) {  // diagonal-crossing window only
        const int qg = qt0 + ql;
#pragma unroll
        for (int reg = 0; reg < 16; ++reg) {
          const int keyg = kk + (reg & 3) + 8 * (reg >> 2) + hi4;
          S[reg] = (keyg > qg) ? -1e30f : S[reg];
        }
      }
      // online softmax (exp2 domain), defer-max; verified shfl reduces
      float t0 = fmaxf(fmaxf(fmaxf(S[0], S[1]), fmaxf(S[2], S[3])),
                       fmaxf(fmaxf(S[4], S[5]), fmaxf(S[6], S[7])));
      float t1 = fmaxf(fmaxf(fmaxf(S[8], S[9]), fmaxf(S[10], S[11])),
                       fmaxf(fmaxf(S[12], S[13]), fmaxf(S[14], S[15])));
      float tmax = fmaxf(t0, t1);
      tmax = fmaxf(tmax, __shfl_xor(tmax, 32));
      if (!__all(tmax <= m + 11.5f)) {
        const float mn = fmaxf(m, tmax);
        const float alpha = __builtin_amdgcn_exp2f(m - mn);
        m = mn;
        lsum *= alpha;
#pragma unroll
        for (int i = 0; i < 16; ++i) { acc0[i] *= alpha; acc1[i] *= alpha; }
      }
#pragma unroll
      for (int reg = 0; reg < 16; ++reg)
        S[reg] = __builtin_amdgcn_exp2f(S[reg] - m);
      float rs = ((S[0] + S[1]) + (S[2] + S[3])) + ((S[4] + S[5]) + (S[6] + S[7])) +
                 ((S[8] + S[9]) + (S[10] + S[11])) + ((S[12] + S[13]) + (S[14] + S[15]));
      rs += __shfl_xor(rs, 32);
      lsum += rs;
      // P -> bf16 B-fragments: verified pack + shfl_xor(32) + select
      const unsigned a0 = pk2(S[0], S[1]), a1 = pk2(S[2], S[3]);
      const unsigned b0 = pk2(S[4], S[5]), b1 = pk2(S[6], S[7]);
      const unsigned c0 = pk2(S[8], S[9]), c1 = pk2(S[10], S[11]);
      const unsigned d0 = pk2(S[12], S[13]), d1 = pk2(S[14], S[15]);
      const unsigned pa0 = (unsigned)__shfl_xor((int)a0, 32);
      const unsigned pa1 = (unsigned)__shfl_xor((int)a1, 32);
      const unsigned pb0 = (unsigned)__shfl_xor((int)b0, 32);
      const unsigned pb1 = (unsigned)__shfl_xor((int)b1, 32);
      const unsigned pc0 = (unsigned)__shfl_xor((int)c0, 32);
      const unsigned pc1 = (unsigned)__shfl_xor((int)c1, 32);
      const unsigned pd0 = (unsigned)__shfl_xor((int)d0, 32);
      const unsigned pd1 = (unsigned)__shfl_xor((int)d1, 32);
      const bool hb_ = (hi != 0);
      uint4v wk0, wk1;
      wk0[0] = hb_ ? pb0 : a0;  wk0[1] = hb_ ? pb1 : a1;
      wk0[2] = hb_ ? b0 : pa0;  wk0[3] = hb_ ? b1 : pa1;
      wk1[0] = hb_ ? pd0 : c0;  wk1[1] = hb_ ? pd1 : c1;
      wk1[2] = hb_ ? d0 : pc0;  wk1[3] = hb_ ? d1 : pc1;
      const bf16x8 pf0 = __builtin_bit_cast(bf16x8, wk0);
      const bf16x8 pf1 = __builtin_bit_cast(bf16x8, wk1);
      acc0 = __builtin_amdgcn_mfma_f32_32x32x16_bf16(vf00, pf0, acc0, 0, 0, 0);
      acc0 = __builtin_amdgcn_mfma_f32_32x32x16_bf16(vf01, pf1, acc0, 0, 0, 0);
      acc1 = __builtin_amdgcn_mfma_f32_32x32x16_bf16(vf10, pf0, acc1, 0, 0, 0);
      acc1 = __builtin_amdgcn_mfma_f32_32x32x16_bf16(vf11, pf1, acc1, 0, 0, 0);
    }
    __syncthreads();  // stage(next) drained + buf[cur] reads done
  }

  __syncthreads();  // st -> red overlay transition
#pragma unroll
  for (int g = 0; g < 4; ++g) {
    f32x4 t0, t1;
#pragma unroll
    for (int i = 0; i < 4; ++i) { t0[i] = acc0[g * 4 + i]; t1[i] = acc1[g * 4 + i]; }
    *(f32x4*)&sm.red.acc[wave][lane][g * 4] = t0;
    *(f32x4*)&sm.red.acc[wave][lane][16 + g * 4] = t1;
  }
  if (lane < 32) {
    sm.red.ml[wave][lane][0] = m;
    sm.red.ml[wave][lane][1] = lsum;
  }
  __syncthreads();

  // 4-way wave combine per tile; write UNNORMALIZED partial + (M,L)
  const int p2 = wave >> 2, s4 = wave & 3;
  const int w0 = p2 * 4;
  const int hrow0 = (s4 & 1) * 16 + hi8;
  const int nt = s4 >> 1;
  const int rb = nt * 16 + ((hrow0 >> 3) << 2);
  float mw[4], lw[4];
#pragma unroll
  for (int w2 = 0; w2 < 4; ++w2) {
    mw[w2] = sm.red.ml[w0 + w2][ql][0];
    lw[w2] = sm.red.ml[w0 + w2][ql][1];
  }
  const float M = fmaxf(fmaxf(mw[0], mw[1]), fmaxf(mw[2], mw[3]));
  float L = 0.f;
  f32x4 o0 = f32x4{0.f, 0.f, 0.f, 0.f}, o1 = f32x4{0.f, 0.f, 0.f, 0.f};
#pragma unroll
  for (int w2 = 0; w2 < 4; ++w2) {
    const float e = __builtin_amdgcn_exp2f(mw[w2] - M);
    L += e * lw[w2];
    const f32x4 A0 = *(const f32x4*)&sm.red.acc[w0 + w2][ql][rb];
    const f32x4 A1 = *(const f32x4*)&sm.red.acc[w0 + w2][ql + 32][rb];
    o0[0] += e * A0[0]; o0[1] += e * A0[1]; o0[2] += e * A0[2]; o0[3] += e * A0[3];
    o1[0] += e * A1[0]; o1[1] += e * A1[1]; o1[2] += e * A1[2]; o1[3] += e * A1[3];
  }
  float* pa = pacc + (((size_t)widx * 64) + p2 * 32 + ql) * 64 + s4 * 16 + hi8;
  *(f32x4*)(pa) = o0;
  *(f32x4*)(pa + 4) = o1;
  if (s4 == 0 && hi == 0) {
    float* pm = pml + (((size_t)widx * 64) + p2 * 32 + ql) * 2;
    pm[0] = M;
    pm[1] = L;
  }
}

// ---------------------------------------------------------------------------
// Kernel 4: merge the two KV-halves -> final output (R12-verified).
// ---------------------------------------------------------------------------
__global__ __launch_bounds__(256) void comb_kernel(
    const float* __restrict__ pacc, const float* __restrict__ pml,
    float* __restrict__ out) {
  const int g = blockIdx.x;  // b*64 + qj
  const int qj = g & 63, b = g >> 6;
  const int t = threadIdx.x;
  const int q = t & 63, hq = t >> 6;
  const size_t i0 = (size_t)(2 * g) * 64 + q;
  const size_t i1 = (size_t)(2 * g + 1) * 64 + q;
  const float m0 = pml[i0 * 2], l0 = pml[i0 * 2 + 1];
  const float m1 = pml[i1 * 2], l1 = pml[i1 * 2 + 1];
  const float M = fmaxf(m0, m1);
  const float e0 = __builtin_amdgcn_exp2f(m0 - M);
  const float e1 = __builtin_amdgcn_exp2f(m1 - M);
  const float invL = 1.0f / (e0 * l0 + e1 * l1);
  const float* A0 = pacc + i0 * 64 + hq * 16;
  const float* A1 = pacc + i1 * 64 + hq * 16;
  float* op = out + ((size_t)b * T + qj * 64 + q) * H + hq * 16;
#pragma unroll
  for (int j = 0; j < 4; ++j) {
    const f32x4 x0 = *(const f32x4*)(A0 + j * 4);
    const f32x4 x1 = *(const f32x4*)(A1 + j * 4);
    f32x4 r;
#pragma unroll
    for (int i2 = 0; i2 < 4; ++i2) r[i2] = (e0 * x0[i2] + e1 * x1[i2]) * invL;
    *(f32x4*)(op + j * 4) = r;
  }
}

// ---------------------------------------------------------------------------
extern "C" void kernel_launch(void* const* d_in, const int* in_sizes, int n_in,
                              void* d_out, int out_size, void* d_ws,
                              size_t ws_size, hipStream_t stream) {
  const float* x = (const float*)d_in[0];
  const float* Wk = (const float*)d_in[1];
  const float* Wq = (const float*)d_in[2];
  const float* Wv = (const float*)d_in[3];
  float* out = (float*)d_out;
  char* ws = (char*)d_ws;
  const size_t SZ = (size_t)B * T * H * sizeof(bf16_t);  // 2 MB each
  bf16_t* qb = (bf16_t*)ws;
  bf16_t* kb = (bf16_t*)(ws + SZ);
  bf16_t* vT = (bf16_t*)(ws + 2 * SZ);
  bf16_t* WT = (bf16_t*)(ws + 3 * SZ);          // 384 KB
  float* pml = (float*)(ws + 7 * 1024 * 1024);  // 512*64*2 f32 = 256 KB
  float* pacc = (float*)(ws + 8 * 1024 * 1024); // 512*64*64 f32 = 8 MB

  wconv_kernel<<<(3 * H * C + 255) / 256, 256, 0, stream>>>(Wk, Wq, Wv, WT);
  proj_kernel<<<(B * T) / 32, 512, 0, stream>>>(x, WT, qb, kb, vT);
  flash_kernel<<<dim3(512), 512, 0, stream>>>(qb, kb, vT, pacc, pml);
  comb_kernel<<<dim3(256), 256, 0, stream>>>(pacc, pml, out);
}